// Round 9
// baseline (262.750 us; speedup 1.0000x reference)
//
#include <hip/hip_runtime.h>
#include <hip/hip_bf16.h>
#include <cmath>
#include <cstdint>

#define V_   10000
#define D_   300
#define P_   100
#define B_   32
#define T_   2048
#define NC_  2
#define CP_  450      // packed used cols: sum_p e(p), e = 3+p/25
#define CPAD 464      // 29 groups of 16 floats; every 16-group 64B-aligned

// 8 pattern-groups (pattern-aligned, <=60 cols): packed-col starts + pattern starts
__device__ __constant__ int GC0c[9] = {0, 57, 107, 159, 215, 270, 330, 390, 450};
__device__ __constant__ int GP0c[9] = {0, 19, 33, 46, 58, 69, 80, 90, 100};

// packed col -> original diag/bias/wc row (p*6 + i)
__device__ __forceinline__ int maprow(int c) {
    if (c < 75)  return (c / 3) * 6 + c % 3;
    if (c < 175) { int q = c - 75;  return (25 + q / 4) * 6 + q % 4; }
    if (c < 300) { int q = c - 175; return (50 + q / 5) * 6 + q % 5; }
    int q = c - 300; return (75 + q / 6) * 6 + q % 6;
}
// first packed col of pattern p
__device__ __forceinline__ int cstart(int p) {
    if (p < 25) return 3 * p;
    if (p < 50) return 75 + 4 * (p - 25);
    if (p < 75) return 175 + 5 * (p - 50);
    return 300 + 6 * (p - 75);
}

// ---------------------------------------------------------------------------
// K0: build dT[d][cp] = diags[maprow(cp)][d], packed bias/wc.
// ---------------------------------------------------------------------------
__global__ __launch_bounds__(256) void k_tr(const float* __restrict__ diags,
                                            const float* __restrict__ bias,
                                            const float* __restrict__ wc,
                                            float* __restrict__ dT,
                                            float* __restrict__ bp,
                                            float* __restrict__ wp) {
    const int idx = blockIdx.x * 256 + threadIdx.x;
    if (idx < CPAD) {
        float b = 0.f, w = 0.f;
        if (idx < CP_) { int r = maprow(idx); b = bias[r]; w = wc[r]; }
        bp[idx] = b; wp[idx] = w;
    }
    if (idx < D_ * CPAD) {
        const int d = idx / CPAD, cp = idx - d * CPAD;
        dT[idx] = (cp < CP_) ? diags[maprow(cp) * D_ + d] : 0.f;
    }
}

// ---------------------------------------------------------------------------
// K1: mt[v][cp] = max(dot + bias, wc). NO LDS, NO barriers.
// Lane owns one v column; 12-deep double-buffered register pipeline of
// coalesced emb loads (issue->consume gap = 384 own-issue cycles, x ~3
// waves/SIMD covers L2 latency); 16 c coefficients arrive as SGPRs.
// 1160 blocks = 8 XCDs x 145 (bijective chunking, ~1.5MB emb slice/XCD).
// ---------------------------------------------------------------------------
__global__ __launch_bounds__(256) void k_gemm(const float* __restrict__ emb,
                                              const float* __restrict__ dT,
                                              const float* __restrict__ bp,
                                              const float* __restrict__ wp,
                                              float* __restrict__ mt) {
    const int bid = blockIdx.x;            // 1160 = 40 v-tiles x 29 c-tiles
    const int xcd = bid & 7, ii = bid >> 3;
    const int ord = xcd * 145 + ii;        // exact bijection (1160 = 8*145)
    const int vt = ord / 29, ct = ord - vt * 29;
    const int cb = ct * 16;
    const int tid = threadIdx.x;
    const int v = vt * 256 + tid;
    const int vc = min(v, V_ - 1);         // tail clamp (store masked)

    const float* ep = emb + vc;
    const float* dr = dT + cb;

    float acc[16] = {};
    float evA[12], evB[12];
    #pragma unroll
    for (int u = 0; u < 12; ++u) evA[u] = ep[(size_t)u * V_];

    #pragma unroll 5
    for (int g = 0; g < 25; ++g) {         // 25 groups of 12 d
        const int d0 = g * 12;
        if (g < 24) {
            #pragma unroll
            for (int u = 0; u < 12; ++u) evB[u] = ep[(size_t)(d0 + 12 + u) * V_];
        }
        #pragma unroll
        for (int u = 0; u < 12; ++u) {
            const float* dg = dr + (size_t)(d0 + u) * CPAD;   // uniform -> s_load
            #pragma unroll
            for (int j = 0; j < 16; ++j)
                acc[j] = fmaf(evA[u], dg[j], acc[j]);
        }
        #pragma unroll
        for (int u = 0; u < 12; ++u) evA[u] = evB[u];
    }

    if (v < V_) {
        #pragma unroll
        for (int j = 0; j < 16; ++j)
            acc[j] = fmaxf(acc[j] + bp[cb + j], wp[cb + j]);
        float* op = mt + (size_t)v * CPAD + cb;
        #pragma unroll
        for (int q = 0; q < 4; ++q)
            *(float4*)(op + q * 4) = make_float4(acc[q*4], acc[q*4+1],
                                                 acc[q*4+2], acc[q*4+3]);
    }
}

// ---------------------------------------------------------------------------
// K2: block = (b, 64 window-starts, pattern-EIGHTH). pg = bid&7 -> on
// round-robin dispatch each XCD re-reads only its ~2.3MB column slice of mt
// (L2-resident). Reg-staged ds_write, stride-61 LDS (61%32=29, odd -> 2-way
// on write AND diagonal read = free). 16.7KB LDS -> ~8 blocks/CU.
// ---------------------------------------------------------------------------
#define SROW 69
#define SST  61

__global__ __launch_bounds__(256) void k_scan(const float* __restrict__ mt,
                                              const int* __restrict__ docs,
                                              const int* __restrict__ doc_lens,
                                              float* __restrict__ part) {
    __shared__ float sm[SROW * SST];       // 16.4 KB
    __shared__ int rowbuf[SROW];
    const int bid = blockIdx.x;            // 8192 = 32b x 32ts x 8pg
    const int pg = bid & 7;
    const int ts = (bid >> 3) & 31;
    const int b  = bid >> 8;
    const int ts0 = ts * 64;
    const int len = doc_lens[b];
    if (ts0 + 3 > len) return;             // invalid segment: k_final skips it
    const int tid = threadIdx.x;
    const int lane = tid & 63, wid = tid >> 6;
    const int nst = min(SROW, min(T_ - ts0, len - ts0));
    const int c0 = GC0c[pg];
    const int cg = GC0c[pg + 1] - c0;      // <= 60

    for (int q = tid; q < nst; q += 256) rowbuf[q] = docs[b * T_ + ts0 + q];
    __syncthreads();
    for (int q = tid; q < (nst << 6); q += 256) {
        const int r = q >> 6, col = q & 63;
        if (col < cg)
            sm[r * SST + col] = mt[(size_t)rowbuf[r] * CPAD + c0 + col];
    }
    __syncthreads();

    const int t = lane;                    // window start within segment
    for (int p = GP0c[pg] + wid; p < GP0c[pg + 1]; p += 4) {
        const int e = 3 + p / 25;          // wave-uniform
        const int cbs = cstart(p) - c0;
        float s = sm[t * SST + cbs];
        for (int i = 1; i < e; ++i) s += sm[(t + i) * SST + cbs + i];
        float val = (ts0 + t + e <= len) ? s : -INFINITY;
        #pragma unroll
        for (int off = 32; off > 0; off >>= 1)
            val = fmaxf(val, __shfl_xor(val, off, 64));
        if (lane == 0) part[((size_t)b * 32 + ts) * P_ + p] = val;
    }
}

// ---------------------------------------------------------------------------
// K3: reduce valid segments, masked layernorm over P, binarize, linear.
// ---------------------------------------------------------------------------
__global__ __launch_bounds__(128) void k_final(const float* __restrict__ part,
                                               const int* __restrict__ doc_lens,
                                               const float* __restrict__ lw,
                                               const float* __restrict__ lb,
                                               float* __restrict__ out) {
    const int b = blockIdx.x;
    const int tid = threadIdx.x;
    __shared__ float sh[P_];
    __shared__ float stats[2];

    const int len = doc_lens[b];
    const int nseg = min(32, (len - 3) / 64 + 1);   // len >= T/2 always

    float s = -INFINITY;
    bool fin = false;
    if (tid < P_) {
        for (int sg = 0; sg < nseg; ++sg)
            s = fmaxf(s, part[((size_t)b * 32 + sg) * P_ + tid]);
        fin = !isinf(s);
        sh[tid] = s;
    }
    __syncthreads();
    if (tid == 0) {
        int n = 0; float sum = 0.f;
        for (int p = 0; p < P_; p++) {
            float x = sh[p];
            if (!isinf(x)) { n++; sum += x; }
        }
        float mean = sum / (float)n;
        float var = 0.f;
        for (int p = 0; p < P_; p++) {
            float x = sh[p];
            if (!isinf(x)) { float d = x - mean; var += d * d; }
        }
        var /= (float)n;
        stats[0] = mean;
        stats[1] = 1.f / sqrtf(var + 1e-5f);
    }
    __syncthreads();
    if (tid < P_) {
        float norm = fin ? (s - stats[0]) * stats[1] : s;
        sh[tid] = (norm > 0.f) ? 1.f : 0.f;
    }
    __syncthreads();
    if (tid < NC_) {
        float accv = lb[tid];
        for (int p = 0; p < P_; p++) accv += sh[p] * lw[tid * P_ + p];
        out[b * NC_ + tid] = accv;
    }
}

extern "C" void kernel_launch(void* const* d_in, const int* in_sizes, int n_in,
                              void* d_out, int out_size, void* d_ws, size_t ws_size,
                              hipStream_t stream) {
    const float* emb   = (const float*)d_in[0];   // (300, 10000)
    const float* diags = (const float*)d_in[1];   // (600, 300)
    const float* bias  = (const float*)d_in[2];   // (600, 1)
    const float* wc    = (const float*)d_in[3];   // (100, 6)
    const float* lw    = (const float*)d_in[4];   // (2, 100)
    const float* lb    = (const float*)d_in[5];   // (2,)
    const int*   docs  = (const int*)d_in[6];     // (32, 2048)
    const int*   dlens = (const int*)d_in[7];     // (32,)
    float* out = (float*)d_out;                   // (32, 2)

    float* mt   = (float*)d_ws;                               // 10000*464*4 = 18.56 MB
    float* dT   = mt + (size_t)V_ * CPAD;                     // 300*464
    float* bp   = dT + (size_t)D_ * CPAD;                     // 464
    float* wp   = bp + CPAD;                                  // 464
    float* part = wp + CPAD;                                  // 32*32*100 floats

    k_tr   <<<dim3(544),  256, 0, stream>>>(diags, bias, wc, dT, bp, wp);
    k_gemm <<<dim3(1160), 256, 0, stream>>>(emb, dT, bp, wp, mt);
    k_scan <<<dim3(8192), 256, 0, stream>>>(mt, docs, dlens, part);
    k_final<<<dim3(B_),   128, 0, stream>>>(part, dlens, lw, lb, out);
}

// Round 11
// 154.795 us; speedup vs baseline: 1.6974x; 1.6974x over previous
//
#include <hip/hip_runtime.h>
#include <hip/hip_bf16.h>
#include <cmath>
#include <cstdint>

#define V_   10000
#define D_   300
#define P_   100
#define B_   32
#define T_   2048
#define NC_  2
#define CP_  450      // packed used cols: sum_p e(p), e = 3+p/25
#define CPAD 464      // 29 groups of 16 floats; 64B-aligned groups

// 8 pattern-groups (pattern-aligned, <=60 cols): packed-col starts + pattern starts
__device__ __constant__ int GC0c[9] = {0, 57, 107, 159, 215, 270, 330, 390, 450};
__device__ __constant__ int GP0c[9] = {0, 19, 33, 46, 58, 69, 80, 90, 100};

// packed col -> original diag/bias/wc row (p*6 + i)
__device__ __forceinline__ int maprow(int c) {
    if (c < 75)  return (c / 3) * 6 + c % 3;
    if (c < 175) { int q = c - 75;  return (25 + q / 4) * 6 + q % 4; }
    if (c < 300) { int q = c - 175; return (50 + q / 5) * 6 + q % 5; }
    int q = c - 300; return (75 + q / 6) * 6 + q % 6;
}
// first packed col of pattern p
__device__ __forceinline__ int cstart(int p) {
    if (p < 25) return 3 * p;
    if (p < 50) return 75 + 4 * (p - 25);
    if (p < 75) return 175 + 5 * (p - 50);
    return 300 + 6 * (p - 75);
}

// ---------------------------------------------------------------------------
// K0: build dT[d][cp] = diags[maprow(cp)][d], packed bias/wc.
// ---------------------------------------------------------------------------
__global__ __launch_bounds__(256) void k_tr(const float* __restrict__ diags,
                                            const float* __restrict__ bias,
                                            const float* __restrict__ wc,
                                            float* __restrict__ dT,
                                            float* __restrict__ bp,
                                            float* __restrict__ wp) {
    const int idx = blockIdx.x * 256 + threadIdx.x;
    if (idx < CPAD) {
        float b = 0.f, w = 0.f;
        if (idx < CP_) { int r = maprow(idx); b = bias[r]; w = wc[r]; }
        bp[idx] = b; wp[idx] = w;
    }
    if (idx < D_ * CPAD) {
        const int d = idx / CPAD, cp = idx - d * CPAD;
        dT[idx] = (cp < CP_) ? diags[maprow(cp) * D_ + d] : 0.f;
    }
}

// ---------------------------------------------------------------------------
// K1 (UNCHANGED from R8, proven 55us): mt[v][cp] = max(dot + bias, wc).
// NO LDS, NO barriers. Lane owns one v column; depth-6 double-buffered
// register pipeline of coalesced emb loads; 16 c coefs arrive as SGPRs.
// 1160 blocks = 8 XCDs x 145 (bijective chunking, ~1.5MB emb slice/XCD).
// ---------------------------------------------------------------------------
__global__ __launch_bounds__(256) void k_gemm(const float* __restrict__ emb,
                                              const float* __restrict__ dT,
                                              const float* __restrict__ bp,
                                              const float* __restrict__ wp,
                                              float* __restrict__ mt) {
    const int bid = blockIdx.x;            // 1160 = 40 v-tiles x 29 c-tiles
    const int xcd = bid & 7, ii = bid >> 3;
    const int ord = xcd * 145 + ii;        // exact bijection (1160 = 8*145)
    const int vt = ord / 29, ct = ord - vt * 29;
    const int cb = ct * 16;
    const int tid = threadIdx.x;
    const int v = vt * 256 + tid;
    const int vc = min(v, V_ - 1);         // tail clamp (store masked)

    const float* ep = emb + vc;
    const float* dr = dT + cb;

    float acc[16] = {};
    float evA[6], evB[6];
    #pragma unroll
    for (int u = 0; u < 6; ++u) evA[u] = ep[(size_t)u * V_];

    #pragma unroll 2
    for (int g = 0; g < 50; ++g) {
        const int d0 = g * 6;
        if (g < 49) {
            #pragma unroll
            for (int u = 0; u < 6; ++u) evB[u] = ep[(size_t)(d0 + 6 + u) * V_];
        }
        #pragma unroll
        for (int u = 0; u < 6; ++u) {
            const float* dg = dr + (size_t)(d0 + u) * CPAD;   // uniform -> s_load
            #pragma unroll
            for (int j = 0; j < 16; ++j)
                acc[j] = fmaf(evA[u], dg[j], acc[j]);
        }
        #pragma unroll
        for (int u = 0; u < 6; ++u) evA[u] = evB[u];
    }

    if (v < V_) {
        #pragma unroll
        for (int j = 0; j < 16; ++j)
            acc[j] = fmaxf(acc[j] + bp[cb + j], wp[cb + j]);
        float* op = mt + (size_t)v * CPAD + cb;
        #pragma unroll
        for (int q = 0; q < 4; ++q)
            *(float4*)(op + q * 4) = make_float4(acc[q*4], acc[q*4+1],
                                                 acc[q*4+2], acc[q*4+3]);
    }
}

// ---------------------------------------------------------------------------
// K2: block = (b, 64 window-starts, pattern-eighth). pg = bid&7 -> each XCD
// re-reads only its ~2.3MB column slice of mt (L2-resident).
// STAGING IS NOW float4: 16 units/row from 4-aligned base c0a (4x fewer VMEM
// gather instrs than R8's scalar path — that was the hidden ~50us).
// LDS: SST=65 (odd) -> write & diagonal-read conflicts <=2-way (free).
// ---------------------------------------------------------------------------
#define SROW 69
#define SST  65

__global__ __launch_bounds__(256) void k_scan(const float* __restrict__ mt,
                                              const int* __restrict__ docs,
                                              const int* __restrict__ doc_lens,
                                              float* __restrict__ part) {
    __shared__ float sm[SROW * SST];       // 17.9 KB
    __shared__ int rowbuf[SROW];
    const int bid = blockIdx.x;            // 8192 = 32b x 32ts x 8pg
    const int pg = bid & 7;
    const int ts = (bid >> 3) & 31;
    const int b  = bid >> 8;
    const int ts0 = ts * 64;
    const int len = doc_lens[b];
    if (ts0 + 3 > len) return;             // invalid segment: k_final skips it
    const int tid = threadIdx.x;
    const int lane = tid & 63, wid = tid >> 6;
    const int nst = min(SROW, min(T_ - ts0, len - ts0));
    const int c0 = GC0c[pg];
    const int c0a = c0 & ~3;               // 16B-aligned load base
    const int cg = GC0c[pg + 1] - c0;      // <= 60
    const int nf4 = (c0 - c0a + cg + 3) >> 2;   // float4 units per row (<=16)

    for (int q = tid; q < nst; q += 256) rowbuf[q] = docs[b * T_ + ts0 + q];
    __syncthreads();
    for (int q = tid; q < (nst << 4); q += 256) {
        const int r = q >> 4, c4 = q & 15;
        if (c4 < nf4) {
            const float4 vv = *(const float4*)(mt + (size_t)rowbuf[r] * CPAD
                                               + c0a + (c4 << 2));
            const int base = r * SST + (c4 << 2);
            sm[base]     = vv.x;
            sm[base + 1] = vv.y;
            sm[base + 2] = vv.z;
            sm[base + 3] = vv.w;
        }
    }
    __syncthreads();

    const int t = lane;                    // window start within segment
    for (int p = GP0c[pg] + wid; p < GP0c[pg + 1]; p += 4) {
        const int e = 3 + p / 25;          // wave-uniform
        const int cbs = cstart(p) - c0a;
        float s = sm[t * SST + cbs];
        for (int i = 1; i < e; ++i) s += sm[(t + i) * SST + cbs + i];
        float val = (ts0 + t + e <= len) ? s : -INFINITY;
        #pragma unroll
        for (int off = 32; off > 0; off >>= 1)
            val = fmaxf(val, __shfl_xor(val, off, 64));
        if (lane == 0) part[((size_t)b * 32 + ts) * P_ + p] = val;
    }
}

// ---------------------------------------------------------------------------
// K3: reduce valid segments, masked layernorm over P, binarize, linear.
// ---------------------------------------------------------------------------
__global__ __launch_bounds__(128) void k_final(const float* __restrict__ part,
                                               const int* __restrict__ doc_lens,
                                               const float* __restrict__ lw,
                                               const float* __restrict__ lb,
                                               float* __restrict__ out) {
    const int b = blockIdx.x;
    const int tid = threadIdx.x;
    __shared__ float sh[P_];
    __shared__ float stats[2];

    const int len = doc_lens[b];
    const int nseg = min(32, (len - 3) / 64 + 1);   // len >= T/2 always

    float s = -INFINITY;
    bool fin = false;
    if (tid < P_) {
        for (int sg = 0; sg < nseg; ++sg)
            s = fmaxf(s, part[((size_t)b * 32 + sg) * P_ + tid]);
        fin = !isinf(s);
        sh[tid] = s;
    }
    __syncthreads();
    if (tid == 0) {
        int n = 0; float sum = 0.f;
        for (int p = 0; p < P_; p++) {
            float x = sh[p];
            if (!isinf(x)) { n++; sum += x; }
        }
        float mean = sum / (float)n;
        float var = 0.f;
        for (int p = 0; p < P_; p++) {
            float x = sh[p];
            if (!isinf(x)) { float d = x - mean; var += d * d; }
        }
        var /= (float)n;
        stats[0] = mean;
        stats[1] = 1.f / sqrtf(var + 1e-5f);
    }
    __syncthreads();
    if (tid < P_) {
        float norm = fin ? (s - stats[0]) * stats[1] : s;
        sh[tid] = (norm > 0.f) ? 1.f : 0.f;
    }
    __syncthreads();
    if (tid < NC_) {
        float accv = lb[tid];
        for (int p = 0; p < P_; p++) accv += sh[p] * lw[tid * P_ + p];
        out[b * NC_ + tid] = accv;
    }
}

extern "C" void kernel_launch(void* const* d_in, const int* in_sizes, int n_in,
                              void* d_out, int out_size, void* d_ws, size_t ws_size,
                              hipStream_t stream) {
    const float* emb   = (const float*)d_in[0];   // (300, 10000)
    const float* diags = (const float*)d_in[1];   // (600, 300)
    const float* bias  = (const float*)d_in[2];   // (600, 1)
    const float* wc    = (const float*)d_in[3];   // (100, 6)
    const float* lw    = (const float*)d_in[4];   // (2, 100)
    const float* lb    = (const float*)d_in[5];   // (2,)
    const int*   docs  = (const int*)d_in[6];     // (32, 2048)
    const int*   dlens = (const int*)d_in[7];     // (32,)
    float* out = (float*)d_out;                   // (32, 2)

    float* mt   = (float*)d_ws;                               // 10000*464*4 = 18.56 MB
    float* dT   = mt + (size_t)V_ * CPAD;                     // 300*464
    float* bp   = dT + (size_t)D_ * CPAD;                     // 464
    float* wp   = bp + CPAD;                                  // 464
    float* part = wp + CPAD;                                  // 32*32*100 floats

    k_tr   <<<dim3(544),  256, 0, stream>>>(diags, bias, wc, dT, bp, wp);
    k_gemm <<<dim3(1160), 256, 0, stream>>>(emb, dT, bp, wp, mt);
    k_scan <<<dim3(8192), 256, 0, stream>>>(mt, docs, dlens, part);
    k_final<<<dim3(B_),   128, 0, stream>>>(part, dlens, lw, lb, out);
}